// Round 7
// baseline (385.279 us; speedup 1.0000x reference)
//
#include <hip/hip_runtime.h>
#include <math.h>

#define N_NODES 100000
#define N_EDGES 1600000
#define IN_F 128
#define OUT_F 64
#define NEG_SLOPE 0.2f

#define NBUCK 391          // ceil(N_NODES / 256): bucket = 256 consecutive node ids
#define PB 512             // edge-slice blocks for hist/scatter
#define EPB (N_EDGES / PB) // 3125 edges per slice

#define FS 132             // LDS row stride (uints) for packed feat/W tiles

typedef __attribute__((ext_vector_type(8))) short short8;
typedef __attribute__((ext_vector_type(4))) float f32x4;

__device__ __forceinline__ float wsum(float v) {
    #pragma unroll
    for (int off = 32; off; off >>= 1) v += __shfl_xor(v, off);
    return v;
}

// split f32 -> bf16 hi/lo packed in one uint: (hi16<<16)|lo16, x ~= hi + lo
__device__ __forceinline__ unsigned pack_bf(float f) {
    unsigned u  = __float_as_uint(f);
    unsigned hi = u & 0xffff0000u;
    float    lo = f - __uint_as_float(hi);
    return hi | (__float_as_uint(lo) >> 16);
}

__device__ __forceinline__ void unpack8(uint4 p0, uint4 p1, short8& hi, short8& lo) {
    hi[0] = (short)(p0.x >> 16); lo[0] = (short)(p0.x & 0xffffu);
    hi[1] = (short)(p0.y >> 16); lo[1] = (short)(p0.y & 0xffffu);
    hi[2] = (short)(p0.z >> 16); lo[2] = (short)(p0.z & 0xffffu);
    hi[3] = (short)(p0.w >> 16); lo[3] = (short)(p0.w & 0xffffu);
    hi[4] = (short)(p1.x >> 16); lo[4] = (short)(p1.x & 0xffffu);
    hi[5] = (short)(p1.y >> 16); lo[5] = (short)(p1.y & 0xffffu);
    hi[6] = (short)(p1.z >> 16); lo[6] = (short)(p1.z & 0xffffu);
    hi[7] = (short)(p1.w >> 16); lo[7] = (short)(p1.w & 0xffffu);
}

// ---------------- GEMM via split-bf16 MFMA: z0 = onorm*(feat@W^T), fused el/er ----
// Block = 64 nodes, 4 waves; wave = 16 nodes x 64 out-feats.
// D = Ahi*Bhi + Ahi*Blo + Alo*Bhi (f32 acc) ~ f32 GEMM to ~2^-16 rel.
__global__ __launch_bounds__(256) void k_gemm(
        const float* __restrict__ feat, const float* __restrict__ W,
        const float* __restrict__ attn_l, const float* __restrict__ attn_r,
        const float* __restrict__ onorm, float* __restrict__ z0,
        float* __restrict__ el, float* __restrict__ er) {
    __shared__ __align__(16) unsigned flds[64 * FS];   // 64 nodes x 128 k, packed
    __shared__ __align__(16) unsigned wlds[64 * FS];   // 64 outf x 128 k, packed
    int t = threadIdx.x;
    int n0 = blockIdx.x * 64;

    #pragma unroll
    for (int j = 0; j < 8; ++j) {              // 2048 float4-quads each for W, feat
        int idx = t + j * 256;
        int row = idx >> 5, k4 = (idx & 31) * 4;
        float4 wv = *(const float4*)&W[row * IN_F + k4];
        unsigned* wp = &wlds[row * FS + k4];
        wp[0] = pack_bf(wv.x); wp[1] = pack_bf(wv.y);
        wp[2] = pack_bf(wv.z); wp[3] = pack_bf(wv.w);
        int g = n0 + row;
        float4 fv = {0.f, 0.f, 0.f, 0.f};
        if (g < N_NODES) fv = *(const float4*)&feat[(size_t)g * IN_F + k4];
        unsigned* fp = &flds[row * FS + k4];
        fp[0] = pack_bf(fv.x); fp[1] = pack_bf(fv.y);
        fp[2] = pack_bf(fv.z); fp[3] = pack_bf(fv.w);
    }
    __syncthreads();

    int lane = t & 63, wv_ = t >> 6;
    int quad = lane >> 4, nl = lane & 15;
    int mrow = wv_ * 16 + nl;                  // A-operand node row for this lane

    f32x4 acc[4];
    #pragma unroll
    for (int nt = 0; nt < 4; ++nt) acc[nt] = (f32x4){0.f, 0.f, 0.f, 0.f};

    #pragma unroll
    for (int ks = 0; ks < 4; ++ks) {
        int ko = ks * 32 + quad * 8;
        const uint4* ap = (const uint4*)&flds[mrow * FS + ko];
        uint4 a0 = ap[0], a1 = ap[1];
        short8 ahi, alo; unpack8(a0, a1, ahi, alo);
        #pragma unroll
        for (int nt = 0; nt < 4; ++nt) {
            const uint4* bp = (const uint4*)&wlds[(nt * 16 + nl) * FS + ko];
            uint4 b0 = bp[0], b1 = bp[1];
            short8 bhi, blo; unpack8(b0, b1, bhi, blo);
            acc[nt] = __builtin_amdgcn_mfma_f32_16x16x32_bf16(ahi, bhi, acc[nt], 0, 0, 0);
            acc[nt] = __builtin_amdgcn_mfma_f32_16x16x32_bf16(ahi, blo, acc[nt], 0, 0, 0);
            acc[nt] = __builtin_amdgcn_mfma_f32_16x16x32_bf16(alo, bhi, acc[nt], 0, 0, 0);
        }
    }

    // C/D layout: col n = nt*16 + nl, row m (node within wave tile) = quad*4 + r
    float al4[4], ar4[4];
    #pragma unroll
    for (int nt = 0; nt < 4; ++nt) { al4[nt] = attn_l[nt * 16 + nl]; ar4[nt] = attn_r[nt * 16 + nl]; }
    float elp[4] = {0.f, 0.f, 0.f, 0.f}, erp[4] = {0.f, 0.f, 0.f, 0.f};
    #pragma unroll
    for (int nt = 0; nt < 4; ++nt)
        #pragma unroll
        for (int r = 0; r < 4; ++r) {
            elp[r] += acc[nt][r] * al4[nt];
            erp[r] += acc[nt][r] * ar4[nt];
        }
    #pragma unroll
    for (int off = 1; off <= 8; off <<= 1)
        #pragma unroll
        for (int r = 0; r < 4; ++r) {
            elp[r] += __shfl_xor(elp[r], off);
            erp[r] += __shfl_xor(erp[r], off);
        }
    int gbase = n0 + wv_ * 16 + quad * 4;
    if (nl == 0) {
        #pragma unroll
        for (int r = 0; r < 4; ++r) {
            int g = gbase + r;
            if (g < N_NODES) { el[g] = elp[r]; er[g] = erp[r]; }
        }
    }
    #pragma unroll
    for (int r = 0; r < 4; ++r) {
        int g = gbase + r;
        if (g < N_NODES) {
            float on = onorm[g];
            #pragma unroll
            for (int nt = 0; nt < 4; ++nt)
                z0[(size_t)g * OUT_F + nt * 16 + nl] = acc[nt][r] * on;
        }
    }
}

// ---------------- per-block bucket histograms (dst AND src), no global atomics ----
__global__ __launch_bounds__(256) void k_hist(
        const int* __restrict__ src, const int* __restrict__ dst,
        int* __restrict__ cntd, int* __restrict__ cnts) {
    __shared__ int hd[NBUCK], hs[NBUCK];
    int t = threadIdx.x, b = blockIdx.x;
    for (int k = t; k < NBUCK; k += 256) { hd[k] = 0; hs[k] = 0; }
    __syncthreads();
    int base = b * EPB;
    for (int i = t; i < EPB; i += 256) {
        atomicAdd(&hd[dst[base + i] >> 8], 1);   // LDS atomics (on-CU)
        atomicAdd(&hs[src[base + i] >> 8], 1);
    }
    __syncthreads();
    for (int k = t; k < NBUCK; k += 256) {
        cntd[k * PB + b] = hd[k];
        cnts[k * PB + b] = hs[k];
    }
}

// ---------------- bucket totals = column sums of count matrices -------------------
__global__ __launch_bounds__(256) void k_colsum(const int* __restrict__ cntd,
                                                const int* __restrict__ cnts,
                                                int* __restrict__ totd,
                                                int* __restrict__ tots) {
    __shared__ int s[256];
    int b = blockIdx.x, t = threadIdx.x;
    const int* m; int* o; int k;
    if (b < NBUCK) { m = cntd; o = totd; k = b; }
    else           { m = cnts; o = tots; k = b - NBUCK; }
    s[t] = m[k * PB + t] + m[k * PB + t + 256];
    __syncthreads();
    for (int d = 128; d; d >>= 1) { if (t < d) s[t] += s[t + d]; __syncthreads(); }
    if (t == 0) o[k] = s[0];
}

// ---------------- exclusive scans of bucket totals (both keys) --------------------
__global__ __launch_bounds__(512) void k_bstart(const int* __restrict__ totd,
                                                const int* __restrict__ tots,
                                                int* bstartd, int* bstarts) {
    __shared__ int s[512];
    int t = threadIdx.x;
    int v = (t < NBUCK) ? totd[t] : 0;
    s[t] = v; __syncthreads();
    for (int d = 1; d < 512; d <<= 1) { int a = (t >= d) ? s[t - d] : 0; __syncthreads(); s[t] += a; __syncthreads(); }
    if (t <= NBUCK) bstartd[t] = s[t] - v;
    __syncthreads();
    int v2 = (t < NBUCK) ? tots[t] : 0;
    s[t] = v2; __syncthreads();
    for (int d = 1; d < 512; d <<= 1) { int a = (t >= d) ? s[t - d] : 0; __syncthreads(); s[t] += a; __syncthreads(); }
    if (t <= NBUCK) bstarts[t] = s[t] - v2;
}

// ---------------- per-(bucket,block) offsets, in place, both matrices -------------
__global__ __launch_bounds__(512) void k_blockoff(const int* __restrict__ bstartd,
                                                  const int* __restrict__ bstarts,
                                                  int* cntd, int* cnts) {
    __shared__ int s[512];
    int b = blockIdx.x, t = threadIdx.x;
    int* m; const int* bs; int k;
    if (b < NBUCK) { m = cntd; bs = bstartd; k = b; }
    else           { m = cnts; bs = bstarts; k = b - NBUCK; }
    int c = m[k * PB + t];
    s[t] = c; __syncthreads();
    for (int d = 1; d < 512; d <<= 1) { int a = (t >= d) ? s[t - d] : 0; __syncthreads(); s[t] += a; __syncthreads(); }
    m[k * PB + t] = bs[k] + s[t] - c;
}

// ---------------- src-key scatter (bytes only; independent of el/er) --------------
__global__ __launch_bounds__(256) void k_scatter_src(
        const int* __restrict__ src, const int* __restrict__ offs,
        unsigned char* __restrict__ tmps) {
    __shared__ int lOffS[NBUCK], lFillS[NBUCK];
    int t = threadIdx.x, b = blockIdx.x;
    for (int k = t; k < NBUCK; k += 256) { lOffS[k] = offs[k * PB + b]; lFillS[k] = 0; }
    __syncthreads();
    int base = b * EPB;
    for (int i = t; i < EPB; i += 256) {
        int sN = src[base + i];
        int ks = sN >> 8;
        int rs = atomicAdd(&lFillS[ks], 1);       // LDS atomic
        tmps[lOffS[ks] + rs] = (unsigned char)(sN & 255);
    }
}

// ---------------- src-bucket count -> onorm, plain stores -------------------------
__global__ __launch_bounds__(256) void k_srccnt(
        const unsigned char* __restrict__ tmps, const int* __restrict__ bstarts,
        float* __restrict__ onorm) {
    __shared__ int cnt[256];
    int k = blockIdx.x, t = threadIdx.x;
    cnt[t] = 0; __syncthreads();
    int base = bstarts[k], end = bstarts[k + 1];
    for (int i = base + t; i < end; i += 256)
        atomicAdd(&cnt[tmps[i]], 1);
    __syncthreads();
    int idx = k * 256 + t;
    if (idx < N_NODES) onorm[idx] = rsqrtf((float)max(cnt[t], 1));
}

// ---------------- dst-key scatter: {src|dst_low, pexp} records --------------------
__global__ __launch_bounds__(256) void k_scatter3(
        const int* __restrict__ src, const int* __restrict__ dst,
        const float* __restrict__ el, const float* __restrict__ er,
        const int* __restrict__ offd, int2* __restrict__ tmpd) {
    __shared__ int lOffD[NBUCK], lFillD[NBUCK];
    int t = threadIdx.x, b = blockIdx.x;
    for (int k = t; k < NBUCK; k += 256) { lOffD[k] = offd[k * PB + b]; lFillD[k] = 0; }
    __syncthreads();
    int base = b * EPB;
    for (int i = t; i < EPB; i += 256) {
        int e = base + i;
        int sN = src[e], d = dst[e];
        float v = el[sN] + er[d];
        v = (v > 0.f) ? v : NEG_SLOPE * v;
        float pe = __expf(v);
        int kd = d >> 8;
        int rd = atomicAdd(&lFillD[kd], 1);       // LDS atomic
        int2 rec; rec.x = sN | ((d & 255) << 17); rec.y = __float_as_int(pe);
        tmpd[lOffD[kd] + rd] = rec;
    }
}

// ---------------- per-bucket fine sort -> CSR, rowstart, denom, scales ------------
__global__ __launch_bounds__(256) void k_bucket(
        const int2* __restrict__ tmp, const int* __restrict__ bstart,
        const float* __restrict__ onorm, float2* __restrict__ csr,
        int* __restrict__ rowstart, float* __restrict__ s12, float* __restrict__ s3) {
    __shared__ int   cs[256];
    __shared__ int   excl[256];
    __shared__ int   fill[256];
    __shared__ float dsum[256];
    int k = blockIdx.x, t = threadIdx.x;
    int base = bstart[k], end = bstart[k + 1];
    cs[t] = 0; fill[t] = 0; dsum[t] = 0.f;
    __syncthreads();
    for (int i = base + t; i < end; i += 256)
        atomicAdd(&cs[(tmp[i].x >> 17) & 255], 1);
    __syncthreads();
    int c = cs[t];
    for (int d = 1; d < 256; d <<= 1) {
        int a = (t >= d) ? cs[t - d] : 0;
        __syncthreads();
        cs[t] += a;
        __syncthreads();
    }
    excl[t] = cs[t] - c;
    __syncthreads();
    int idx = k * 256 + t;
    if (idx <= N_NODES) rowstart[idx] = base + excl[t];
    for (int i = base + t; i < end; i += 256) {
        int2 rec = tmp[i];
        int dlow = (rec.x >> 17) & 255;
        int r = atomicAdd(&fill[dlow], 1);
        float pe = __int_as_float(rec.y);
        float2 w;
        w.x = __int_as_float(rec.x & 131071);
        w.y = pe;
        csr[base + excl[dlow] + r] = w;
        atomicAdd(&dsum[dlow], pe);
    }
    __syncthreads();
    if (idx < N_NODES) {
        float inn = sqrtf((float)max(c, 1));
        float rs  = (c > 0) ? inn / dsum[t] : 0.f;
        s12[idx] = onorm[idx] * rs;
        s3[idx]  = rs;
    }
}

// ---------------- SpMM hop: y[d] = sigma[d] * sum_e pexp_e * x[col_e] -------------
// One 16-lane group per node (4 nodes/wave). Per group: walk the row in fully
// unrolled chunks of 8 independent chains: broadcast csr load -> 64B row-quad
// gather. jc=min(j,e-1) keeps control flow uniform (OOB weight zeroed; clamped
// gather re-hits the last edge's line in L1). 8 gathers in flight per wave.
__global__ __launch_bounds__(256) void k_spmm(
        const float* __restrict__ x, const int* __restrict__ rowstart,
        const float2* __restrict__ csr, const float* __restrict__ sigma,
        float* __restrict__ y) {
    int node = blockIdx.x * 16 + (threadIdx.x >> 4);
    int fl = threadIdx.x & 15;
    if (node >= N_NODES) return;
    int b = rowstart[node], e = rowstart[node + 1];
    float4 acc0 = {0.f, 0.f, 0.f, 0.f}, acc1 = {0.f, 0.f, 0.f, 0.f};
    float4 acc2 = {0.f, 0.f, 0.f, 0.f}, acc3 = {0.f, 0.f, 0.f, 0.f};
    for (int i = b; i < e; i += 8) {
        #pragma unroll
        for (int u = 0; u < 8; ++u) {
            int j = i + u;
            int jc = (j < e) ? j : (e - 1);
            float2 w = csr[jc];                    // 16-lane broadcast (8B)
            float vv = (j < e) ? w.y : 0.f;
            const float4 xv = *(const float4*)&x[(size_t)__float_as_int(w.x) * OUT_F + fl * 4];
            float4& a = (u & 2) ? ((u & 1) ? acc3 : acc2) : ((u & 1) ? acc1 : acc0);
            a.x += vv * xv.x; a.y += vv * xv.y; a.z += vv * xv.z; a.w += vv * xv.w;
        }
    }
    float sg = sigma[node];
    float4 r;
    r.x = sg * ((acc0.x + acc1.x) + (acc2.x + acc3.x));
    r.y = sg * ((acc0.y + acc1.y) + (acc2.y + acc3.y));
    r.z = sg * ((acc0.z + acc1.z) + (acc2.z + acc3.z));
    r.w = sg * ((acc0.w + acc1.w) + (acc2.w + acc3.w));
    ((float4*)&y[(size_t)node * OUT_F])[fl] = r;
}

extern "C" void kernel_launch(void* const* d_in, const int* in_sizes, int n_in,
                              void* d_out, int out_size, void* d_ws, size_t ws_size,
                              hipStream_t stream) {
    const float* feat   = (const float*)d_in[0];
    const float* W      = (const float*)d_in[1];
    const float* attn_l = (const float*)d_in[2];
    const float* attn_r = (const float*)d_in[3];
    const int*   src    = (const int*)d_in[4];
    const int*   dst    = (const int*)d_in[5];
    float* out = (float*)d_out;

    char* p = (char*)d_ws;
    auto alloc = [&](size_t elems) {
        void* r = (void*)p;
        p += ((elems * 4 + 255) / 256) * 256;
        return r;
    };
    // region1: z0/zbuf (25.6 MB). Written by gemm, read hop1; hop2 out; hop3 in.
    float* zbuf = (float*)alloc((size_t)N_NODES * OUT_F);
    // region2 (25.6 MB): tmpd (12.8, scatter3->bucket) + tmps (1.6, scatter_src->
    // srccnt); both dead before hop1, where A (hop1 out / hop2 in) is born.
    char* r2 = (char*)alloc((size_t)N_NODES * OUT_F);
    int2*  tmpd = (int2*)r2;
    unsigned char* tmps = (unsigned char*)(r2 + (size_t)N_EDGES * 8);
    float* A    = (float*)r2;

    float2* csr      = (float2*)alloc((size_t)N_EDGES * 2);       // 12.8 MB
    int*    cntd     = (int*)   alloc((size_t)NBUCK * PB);        // 0.8 MB
    int*    cnts     = (int*)   alloc((size_t)NBUCK * PB);        // 0.8 MB
    int*    totd     = (int*)   alloc(NBUCK);
    int*    tots     = (int*)   alloc(NBUCK);
    int*    bstartd  = (int*)   alloc(NBUCK + 1);
    int*    bstarts  = (int*)   alloc(NBUCK + 1);
    int*    rowstart = (int*)   alloc(N_NODES + 1);
    float*  onorm    = (float*) alloc(N_NODES);
    float*  s12      = (float*) alloc(N_NODES);
    float*  s3       = (float*) alloc(N_NODES);
    float*  el       = (float*) alloc(N_NODES);
    float*  er       = (float*) alloc(N_NODES);

    const int NGB = (N_NODES + 63) / 64;   // 1563 gemm blocks

    k_hist       <<<PB,        256, 0, stream>>>(src, dst, cntd, cnts);
    k_colsum     <<<2 * NBUCK, 256, 0, stream>>>(cntd, cnts, totd, tots);
    k_bstart     <<<1,         512, 0, stream>>>(totd, tots, bstartd, bstarts);
    k_blockoff   <<<2 * NBUCK, 512, 0, stream>>>(bstartd, bstarts, cntd, cnts);
    k_scatter_src<<<PB,        256, 0, stream>>>(src, cnts, tmps);
    k_srccnt     <<<NBUCK,     256, 0, stream>>>(tmps, bstarts, onorm);
    k_gemm       <<<NGB,       256, 0, stream>>>(feat, W, attn_l, attn_r, onorm, zbuf, el, er);
    k_scatter3   <<<PB,        256, 0, stream>>>(src, dst, el, er, cntd, tmpd);
    k_bucket     <<<NBUCK,     256, 0, stream>>>(tmpd, bstartd, onorm, csr, rowstart, s12, s3);

    const int nb_spmm = N_NODES / 16;   // one 16-lane group per node
    k_spmm<<<nb_spmm, 256, 0, stream>>>(zbuf, rowstart, csr, s12, A);    // hop 1
    k_spmm<<<nb_spmm, 256, 0, stream>>>(A,    rowstart, csr, s12, zbuf); // hop 2
    k_spmm<<<nb_spmm, 256, 0, stream>>>(zbuf, rowstart, csr, s3,  out);  // hop 3
}

// Round 8
// 321.560 us; speedup vs baseline: 1.1982x; 1.1982x over previous
//
#include <hip/hip_runtime.h>
#include <hip/hip_fp16.h>
#include <math.h>

#define N_NODES 100000
#define N_EDGES 1600000
#define IN_F 128
#define OUT_F 64
#define NEG_SLOPE 0.2f

#define NBUCK 391          // ceil(N_NODES / 256): bucket = 256 consecutive node ids
#define PB 512             // edge-slice blocks for hist/scatter
#define EPB (N_EDGES / PB) // 3125 edges per slice

#define FS 132             // LDS row stride (uints) for packed feat/W tiles

typedef __attribute__((ext_vector_type(8))) short short8;
typedef __attribute__((ext_vector_type(4))) float f32x4;

// split f32 -> bf16 hi/lo packed in one uint: (hi16<<16)|lo16, x ~= hi + lo
__device__ __forceinline__ unsigned pack_bf(float f) {
    unsigned u  = __float_as_uint(f);
    unsigned hi = u & 0xffff0000u;
    float    lo = f - __uint_as_float(hi);
    return hi | (__float_as_uint(lo) >> 16);
}

__device__ __forceinline__ void unpack8(uint4 p0, uint4 p1, short8& hi, short8& lo) {
    hi[0] = (short)(p0.x >> 16); lo[0] = (short)(p0.x & 0xffffu);
    hi[1] = (short)(p0.y >> 16); lo[1] = (short)(p0.y & 0xffffu);
    hi[2] = (short)(p0.z >> 16); lo[2] = (short)(p0.z & 0xffffu);
    hi[3] = (short)(p0.w >> 16); lo[3] = (short)(p0.w & 0xffffu);
    hi[4] = (short)(p1.x >> 16); lo[4] = (short)(p1.x & 0xffffu);
    hi[5] = (short)(p1.y >> 16); lo[5] = (short)(p1.y & 0xffffu);
    hi[6] = (short)(p1.z >> 16); lo[6] = (short)(p1.z & 0xffffu);
    hi[7] = (short)(p1.w >> 16); lo[7] = (short)(p1.w & 0xffffu);
}

// ---------------- GEMM via split-bf16 MFMA: h(fp16) = feat@W^T, fused el/er -------
// Block = 64 nodes, 4 waves; wave = 16 nodes x 64 out-feats.
// D = Ahi*Bhi + Ahi*Blo + Alo*Bhi (f32 acc) ~ f32 GEMM to ~2^-16 rel.
__global__ __launch_bounds__(256) void k_gemm(
        const float* __restrict__ feat, const float* __restrict__ W,
        const float* __restrict__ attn_l, const float* __restrict__ attn_r,
        __half* __restrict__ h16, float* __restrict__ el, float* __restrict__ er) {
    __shared__ __align__(16) unsigned flds[64 * FS];   // 64 nodes x 128 k, packed
    __shared__ __align__(16) unsigned wlds[64 * FS];   // 64 outf x 128 k, packed
    int t = threadIdx.x;
    int n0 = blockIdx.x * 64;

    #pragma unroll
    for (int j = 0; j < 8; ++j) {              // 2048 float4-quads each for W, feat
        int idx = t + j * 256;
        int row = idx >> 5, k4 = (idx & 31) * 4;
        float4 wv = *(const float4*)&W[row * IN_F + k4];
        unsigned* wp = &wlds[row * FS + k4];
        wp[0] = pack_bf(wv.x); wp[1] = pack_bf(wv.y);
        wp[2] = pack_bf(wv.z); wp[3] = pack_bf(wv.w);
        int g = n0 + row;
        float4 fv = {0.f, 0.f, 0.f, 0.f};
        if (g < N_NODES) fv = *(const float4*)&feat[(size_t)g * IN_F + k4];
        unsigned* fp = &flds[row * FS + k4];
        fp[0] = pack_bf(fv.x); fp[1] = pack_bf(fv.y);
        fp[2] = pack_bf(fv.z); fp[3] = pack_bf(fv.w);
    }
    __syncthreads();

    int lane = t & 63, wv_ = t >> 6;
    int quad = lane >> 4, nl = lane & 15;
    int mrow = wv_ * 16 + nl;                  // A-operand node row for this lane

    f32x4 acc[4];
    #pragma unroll
    for (int nt = 0; nt < 4; ++nt) acc[nt] = (f32x4){0.f, 0.f, 0.f, 0.f};

    #pragma unroll
    for (int ks = 0; ks < 4; ++ks) {
        int ko = ks * 32 + quad * 8;
        const uint4* ap = (const uint4*)&flds[mrow * FS + ko];
        uint4 a0 = ap[0], a1 = ap[1];
        short8 ahi, alo; unpack8(a0, a1, ahi, alo);
        #pragma unroll
        for (int nt = 0; nt < 4; ++nt) {
            const uint4* bp = (const uint4*)&wlds[(nt * 16 + nl) * FS + ko];
            uint4 b0 = bp[0], b1 = bp[1];
            short8 bhi, blo; unpack8(b0, b1, bhi, blo);
            acc[nt] = __builtin_amdgcn_mfma_f32_16x16x32_bf16(ahi, bhi, acc[nt], 0, 0, 0);
            acc[nt] = __builtin_amdgcn_mfma_f32_16x16x32_bf16(ahi, blo, acc[nt], 0, 0, 0);
            acc[nt] = __builtin_amdgcn_mfma_f32_16x16x32_bf16(alo, bhi, acc[nt], 0, 0, 0);
        }
    }

    // C/D layout: col n = nt*16 + nl, row m (node within wave tile) = quad*4 + r
    float al4[4], ar4[4];
    #pragma unroll
    for (int nt = 0; nt < 4; ++nt) { al4[nt] = attn_l[nt * 16 + nl]; ar4[nt] = attn_r[nt * 16 + nl]; }
    float elp[4] = {0.f, 0.f, 0.f, 0.f}, erp[4] = {0.f, 0.f, 0.f, 0.f};
    #pragma unroll
    for (int nt = 0; nt < 4; ++nt)
        #pragma unroll
        for (int r = 0; r < 4; ++r) {
            elp[r] += acc[nt][r] * al4[nt];
            erp[r] += acc[nt][r] * ar4[nt];
        }
    #pragma unroll
    for (int off = 1; off <= 8; off <<= 1)
        #pragma unroll
        for (int r = 0; r < 4; ++r) {
            elp[r] += __shfl_xor(elp[r], off);
            erp[r] += __shfl_xor(erp[r], off);
        }
    int gbase = n0 + wv_ * 16 + quad * 4;
    if (nl == 0) {
        #pragma unroll
        for (int r = 0; r < 4; ++r) {
            int g = gbase + r;
            if (g < N_NODES) { el[g] = elp[r]; er[g] = erp[r]; }
        }
    }
    #pragma unroll
    for (int r = 0; r < 4; ++r) {
        int g = gbase + r;
        if (g < N_NODES) {
            #pragma unroll
            for (int nt = 0; nt < 4; ++nt)
                h16[(size_t)g * OUT_F + nt * 16 + nl] = __float2half(acc[nt][r]);
        }
    }
}

// ---------------- per-block bucket histograms (dst AND src), no global atomics ----
__global__ __launch_bounds__(256) void k_hist(
        const int* __restrict__ src, const int* __restrict__ dst,
        int* __restrict__ cntd, int* __restrict__ cnts) {
    __shared__ int hd[NBUCK], hs[NBUCK];
    int t = threadIdx.x, b = blockIdx.x;
    for (int k = t; k < NBUCK; k += 256) { hd[k] = 0; hs[k] = 0; }
    __syncthreads();
    int base = b * EPB;
    for (int i = t; i < EPB; i += 256) {
        atomicAdd(&hd[dst[base + i] >> 8], 1);   // LDS atomics (on-CU)
        atomicAdd(&hs[src[base + i] >> 8], 1);
    }
    __syncthreads();
    for (int k = t; k < NBUCK; k += 256) {
        cntd[k * PB + b] = hd[k];
        cnts[k * PB + b] = hs[k];
    }
}

// ---------------- bucket totals = column sums of count matrices -------------------
__global__ __launch_bounds__(256) void k_colsum(const int* __restrict__ cntd,
                                                const int* __restrict__ cnts,
                                                int* __restrict__ totd,
                                                int* __restrict__ tots) {
    __shared__ int s[256];
    int b = blockIdx.x, t = threadIdx.x;
    const int* m; int* o; int k;
    if (b < NBUCK) { m = cntd; o = totd; k = b; }
    else           { m = cnts; o = tots; k = b - NBUCK; }
    s[t] = m[k * PB + t] + m[k * PB + t + 256];
    __syncthreads();
    for (int d = 128; d; d >>= 1) { if (t < d) s[t] += s[t + d]; __syncthreads(); }
    if (t == 0) o[k] = s[0];
}

// ---------------- exclusive scans of bucket totals (both keys) --------------------
__global__ __launch_bounds__(512) void k_bstart(const int* __restrict__ totd,
                                                const int* __restrict__ tots,
                                                int* bstartd, int* bstarts) {
    __shared__ int s[512];
    int t = threadIdx.x;
    int v = (t < NBUCK) ? totd[t] : 0;
    s[t] = v; __syncthreads();
    for (int d = 1; d < 512; d <<= 1) { int a = (t >= d) ? s[t - d] : 0; __syncthreads(); s[t] += a; __syncthreads(); }
    if (t <= NBUCK) bstartd[t] = s[t] - v;
    __syncthreads();
    int v2 = (t < NBUCK) ? tots[t] : 0;
    s[t] = v2; __syncthreads();
    for (int d = 1; d < 512; d <<= 1) { int a = (t >= d) ? s[t - d] : 0; __syncthreads(); s[t] += a; __syncthreads(); }
    if (t <= NBUCK) bstarts[t] = s[t] - v2;
}

// ---------------- per-(bucket,block) offsets, in place, both matrices -------------
__global__ __launch_bounds__(512) void k_blockoff(const int* __restrict__ bstartd,
                                                  const int* __restrict__ bstarts,
                                                  int* cntd, int* cnts) {
    __shared__ int s[512];
    int b = blockIdx.x, t = threadIdx.x;
    int* m; const int* bs; int k;
    if (b < NBUCK) { m = cntd; bs = bstartd; k = b; }
    else           { m = cnts; bs = bstarts; k = b - NBUCK; }
    int c = m[k * PB + t];
    s[t] = c; __syncthreads();
    for (int d = 1; d < 512; d <<= 1) { int a = (t >= d) ? s[t - d] : 0; __syncthreads(); s[t] += a; __syncthreads(); }
    m[k * PB + t] = bs[k] + s[t] - c;
}

// ---------------- src-key scatter (bytes only; independent of el/er) --------------
__global__ __launch_bounds__(256) void k_scatter_src(
        const int* __restrict__ src, const int* __restrict__ offs,
        unsigned char* __restrict__ tmps) {
    __shared__ int lOffS[NBUCK], lFillS[NBUCK];
    int t = threadIdx.x, b = blockIdx.x;
    for (int k = t; k < NBUCK; k += 256) { lOffS[k] = offs[k * PB + b]; lFillS[k] = 0; }
    __syncthreads();
    int base = b * EPB;
    for (int i = t; i < EPB; i += 256) {
        int sN = src[base + i];
        int ks = sN >> 8;
        int rs = atomicAdd(&lFillS[ks], 1);       // LDS atomic
        tmps[lOffS[ks] + rs] = (unsigned char)(sN & 255);
    }
}

// ---------------- src-bucket count -> onorm, plain stores -------------------------
__global__ __launch_bounds__(256) void k_srccnt(
        const unsigned char* __restrict__ tmps, const int* __restrict__ bstarts,
        float* __restrict__ onorm) {
    __shared__ int cnt[256];
    int k = blockIdx.x, t = threadIdx.x;
    cnt[t] = 0; __syncthreads();
    int base = bstarts[k], end = bstarts[k + 1];
    for (int i = base + t; i < end; i += 256)
        atomicAdd(&cnt[tmps[i]], 1);
    __syncthreads();
    int idx = k * 256 + t;
    if (idx < N_NODES) onorm[idx] = rsqrtf((float)max(cnt[t], 1));
}

// ---------------- dst-key scatter: {src|dst_low, pexp} records --------------------
__global__ __launch_bounds__(256) void k_scatter3(
        const int* __restrict__ src, const int* __restrict__ dst,
        const float* __restrict__ el, const float* __restrict__ er,
        const int* __restrict__ offd, int2* __restrict__ tmpd) {
    __shared__ int lOffD[NBUCK], lFillD[NBUCK];
    int t = threadIdx.x, b = blockIdx.x;
    for (int k = t; k < NBUCK; k += 256) { lOffD[k] = offd[k * PB + b]; lFillD[k] = 0; }
    __syncthreads();
    int base = b * EPB;
    for (int i = t; i < EPB; i += 256) {
        int e = base + i;
        int sN = src[e], d = dst[e];
        float v = el[sN] + er[d];
        v = (v > 0.f) ? v : NEG_SLOPE * v;
        float pe = __expf(v);
        int kd = d >> 8;
        int rd = atomicAdd(&lFillD[kd], 1);       // LDS atomic
        int2 rec; rec.x = sN | ((d & 255) << 17); rec.y = __float_as_int(pe);
        tmpd[lOffD[kd] + rd] = rec;
    }
}

// ---------------- per-bucket fine sort -> CSR {src, pexp*onorm[src]}, sigma -------
// onorm folded into edge values: hop is y[d] = sigma[d] * sum val_e * x[src_e]
// with sigma = innorm/denom identical for all 3 hops (denom = sum pexp).
__global__ __launch_bounds__(256) void k_bucket(
        const int2* __restrict__ tmp, const int* __restrict__ bstart,
        const float* __restrict__ onorm, float2* __restrict__ csr,
        int* __restrict__ rowstart, float* __restrict__ sigma) {
    __shared__ int   cs[256];
    __shared__ int   excl[256];
    __shared__ int   fill[256];
    __shared__ float dsum[256];
    int k = blockIdx.x, t = threadIdx.x;
    int base = bstart[k], end = bstart[k + 1];
    cs[t] = 0; fill[t] = 0; dsum[t] = 0.f;
    __syncthreads();
    for (int i = base + t; i < end; i += 256)
        atomicAdd(&cs[(tmp[i].x >> 17) & 255], 1);
    __syncthreads();
    int c = cs[t];
    for (int d = 1; d < 256; d <<= 1) {
        int a = (t >= d) ? cs[t - d] : 0;
        __syncthreads();
        cs[t] += a;
        __syncthreads();
    }
    excl[t] = cs[t] - c;
    __syncthreads();
    int idx = k * 256 + t;
    if (idx <= N_NODES) rowstart[idx] = base + excl[t];
    for (int i = base + t; i < end; i += 256) {
        int2 rec = tmp[i];
        int dlow = (rec.x >> 17) & 255;
        int r = atomicAdd(&fill[dlow], 1);
        float pe = __int_as_float(rec.y);
        int sN = rec.x & 131071;
        float2 w;
        w.x = __int_as_float(sN);
        w.y = pe * onorm[sN];
        csr[base + excl[dlow] + r] = w;
        atomicAdd(&dsum[dlow], pe);
    }
    __syncthreads();
    if (idx < N_NODES) {
        float inn = sqrtf((float)max(c, 1));
        sigma[idx] = (c > 0) ? inn / dsum[t] : 0.f;
    }
}

// ---------------- SpMM hop: y[d] = sigma[d] * sum_e val_e * x[col_e] --------------
// x in fp16 (128B rows): one 16-lane group per node, 8B dwordx2 gather per lane,
// 8 independent chains; f32 accumulate. OT = __half (hops 1,2) or float (hop 3).
template<typename OT>
__global__ __launch_bounds__(256) void k_spmm(
        const __half* __restrict__ x, const int* __restrict__ rowstart,
        const float2* __restrict__ csr, const float* __restrict__ sigma,
        OT* __restrict__ y) {
    int node = blockIdx.x * 16 + (threadIdx.x >> 4);
    int fl = threadIdx.x & 15;
    if (node >= N_NODES) return;
    int b = rowstart[node], e = rowstart[node + 1];
    float4 acc0 = {0.f, 0.f, 0.f, 0.f}, acc1 = {0.f, 0.f, 0.f, 0.f};
    float4 acc2 = {0.f, 0.f, 0.f, 0.f}, acc3 = {0.f, 0.f, 0.f, 0.f};
    for (int i = b; i < e; i += 8) {
        #pragma unroll
        for (int u = 0; u < 8; ++u) {
            int j = i + u;
            int jc = (j < e) ? j : (e - 1);
            float2 w = csr[jc];                    // 16-lane broadcast (8B)
            float vv = (j < e) ? w.y : 0.f;
            uint2 pk = *(const uint2*)(x + (size_t)__float_as_int(w.x) * OUT_F + fl * 4);
            float2 f0 = __half22float2(*(__half2*)&pk.x);
            float2 f1 = __half22float2(*(__half2*)&pk.y);
            float4& a = (u & 2) ? ((u & 1) ? acc3 : acc2) : ((u & 1) ? acc1 : acc0);
            a.x += vv * f0.x; a.y += vv * f0.y; a.z += vv * f1.x; a.w += vv * f1.y;
        }
    }
    float sg = sigma[node];
    float4 r;
    r.x = sg * ((acc0.x + acc1.x) + (acc2.x + acc3.x));
    r.y = sg * ((acc0.y + acc1.y) + (acc2.y + acc3.y));
    r.z = sg * ((acc0.z + acc1.z) + (acc2.z + acc3.z));
    r.w = sg * ((acc0.w + acc1.w) + (acc2.w + acc3.w));
    if constexpr (sizeof(OT) == 4) {
        ((float4*)((float*)y + (size_t)node * OUT_F))[fl] = r;
    } else {
        __half2 p0 = __floats2half2_rn(r.x, r.y);
        __half2 p1 = __floats2half2_rn(r.z, r.w);
        uint2 o;
        o.x = *(unsigned*)&p0;
        o.y = *(unsigned*)&p1;
        *(uint2*)((__half*)y + (size_t)node * OUT_F + fl * 4) = o;
    }
}

extern "C" void kernel_launch(void* const* d_in, const int* in_sizes, int n_in,
                              void* d_out, int out_size, void* d_ws, size_t ws_size,
                              hipStream_t stream) {
    const float* feat   = (const float*)d_in[0];
    const float* W      = (const float*)d_in[1];
    const float* attn_l = (const float*)d_in[2];
    const float* attn_r = (const float*)d_in[3];
    const int*   src    = (const int*)d_in[4];
    const int*   dst    = (const int*)d_in[5];
    float* out = (float*)d_out;

    char* p = (char*)d_ws;
    auto alloc = [&](size_t bytes) {
        void* r = (void*)p;
        p += (bytes + 255) & ~(size_t)255;
        return r;
    };
    // region1: hbuf (fp16, 12.8 MB): gemm out -> hop1 in; then y2 (hop2 out, hop3 in).
    __half* hbuf = (__half*)alloc((size_t)N_NODES * OUT_F * 2);
    // region2 (14.4 MB): tmpd (12.8) + tmps (1.6) until k_bucket; then A = y1 (fp16).
    char* r2 = (char*)alloc((size_t)N_EDGES * 8 + (size_t)N_EDGES);
    int2*  tmpd = (int2*)r2;
    unsigned char* tmps = (unsigned char*)(r2 + (size_t)N_EDGES * 8);
    __half* A   = (__half*)r2;

    float2* csr      = (float2*)alloc((size_t)N_EDGES * 8);        // 12.8 MB
    int*    cntd     = (int*)   alloc((size_t)NBUCK * PB * 4);
    int*    cnts     = (int*)   alloc((size_t)NBUCK * PB * 4);
    int*    totd     = (int*)   alloc(NBUCK * 4);
    int*    tots     = (int*)   alloc(NBUCK * 4);
    int*    bstartd  = (int*)   alloc((NBUCK + 1) * 4);
    int*    bstarts  = (int*)   alloc((NBUCK + 1) * 4);
    int*    rowstart = (int*)   alloc((N_NODES + 1) * 4);
    float*  onorm    = (float*) alloc(N_NODES * 4);
    float*  sigma    = (float*) alloc(N_NODES * 4);
    float*  el       = (float*) alloc(N_NODES * 4);
    float*  er       = (float*) alloc(N_NODES * 4);

    const int NGB = (N_NODES + 63) / 64;   // 1563 gemm blocks

    k_gemm       <<<NGB,       256, 0, stream>>>(feat, W, attn_l, attn_r, hbuf, el, er);
    k_hist       <<<PB,        256, 0, stream>>>(src, dst, cntd, cnts);
    k_colsum     <<<2 * NBUCK, 256, 0, stream>>>(cntd, cnts, totd, tots);
    k_bstart     <<<1,         512, 0, stream>>>(totd, tots, bstartd, bstarts);
    k_blockoff   <<<2 * NBUCK, 512, 0, stream>>>(bstartd, bstarts, cntd, cnts);
    k_scatter_src<<<PB,        256, 0, stream>>>(src, cnts, tmps);
    k_srccnt     <<<NBUCK,     256, 0, stream>>>(tmps, bstarts, onorm);
    k_scatter3   <<<PB,        256, 0, stream>>>(src, dst, el, er, cntd, tmpd);
    k_bucket     <<<NBUCK,     256, 0, stream>>>(tmpd, bstartd, onorm, csr, rowstart, sigma);

    const int nb_spmm = N_NODES / 16;   // one 16-lane group per node
    k_spmm<__half><<<nb_spmm, 256, 0, stream>>>(hbuf, rowstart, csr, sigma, A);    // hop 1
    k_spmm<__half><<<nb_spmm, 256, 0, stream>>>(A,    rowstart, csr, sigma, hbuf); // hop 2
    k_spmm<float> <<<nb_spmm, 256, 0, stream>>>(hbuf, rowstart, csr, sigma, out);  // hop 3
}